// Round 7
// baseline (685.355 us; speedup 1.0000x reference)
//
#include <hip/hip_runtime.h>

#define F 3
#define V 512
#define D 8192
#define B 64
#define ITERS 10
#define DW 256  // u32 words per D-row (D/32)
#define NBLK 192

typedef __bf16 bf16_t;
typedef __bf16 bf16x8 __attribute__((ext_vector_type(8)));
typedef float f32x4 __attribute__((ext_vector_type(4)));
typedef unsigned int u32;
typedef unsigned short u16;
typedef u16 u16x8 __attribute__((ext_vector_type(8)));
typedef unsigned long long u64;

// ---------------------------------------------------------------------------
// Values are in {0,+1,-1}. sign bit s=1 <=> v<0; zero bit z=1 <=> v==0.
// dot(A,c) = nzc - 2*popc((As ^ cs) & ~Az)  (exact integers).
//
// Persistent-kernel design (r6 post-mortem): multi-launch pays ~19us per
// dispatch x 23 gaps ~ 430us of the 534us total. Fuse the loop into ONE
// kernel. r3-r5 fusion failures diagnosed: (r3) acquire-polling invalidated
// L2 per poll; (r4/r5) phases ran at 3 waves/CU (0.75/SIMD) with scalar sc1
// staging loads -> latency-naked. v2: 512-thread blocks (2 waves/SIMD),
// r6-verified vectorized phase bodies, plain cached bulk loads, coherence
// via ONE release fence at arrival + ONE acquire fence after spin (r4-proven
// correct), RELAXED polls only.
// ---------------------------------------------------------------------------

__device__ inline int aload(const int* p) {
  return __hip_atomic_load((int*)p, __ATOMIC_RELAXED, __HIP_MEMORY_SCOPE_AGENT);
}

// ---------------------------------------------------------------------------
// init: codebook bit-pack both ways + flag/barrier zeroing.
// Cbits[f][wc][v][j]: d-bit-packed (sim phase, uint4-tiled over d-words)
// CbTb[f][d][vw]:     v-bit-packed (upd phase B-operand LDS expansion)
// ---------------------------------------------------------------------------
__global__ __launch_bounds__(256) void k_init_tr(const float* __restrict__ Csrc,
                                                 u32* __restrict__ Cbits,
                                                 u32* __restrict__ CbTb,
                                                 int* __restrict__ flags) {
  int f = blockIdx.z, vt = blockIdx.y, dt = blockIdx.x;
  __shared__ bf16_t tile[64 * 65];
  int t = threadIdx.x;
  int lane = t & 63;
  int v0 = vt * 64, d0 = dt * 64;
  if (f == 0 && vt == 0 && dt == 0 && t < 64) flags[t] = 0;
#pragma unroll
  for (int p = 0; p < 16; ++p) {
    int q = t + 256 * p;
    int i = q >> 6, j = q & 63;  // j == lane, i uniform per wave
    float x = Csrc[((long)(f * V + v0 + i)) * D + d0 + j];
    tile[i * 65 + j] = (bf16_t)x;
    u64 bal = __ballot(x < 0.f);  // bit l <-> d = d0 + l
    if (lane == 0) {
      int v = v0 + i;
      uint2 wp;
      wp.x = (u32)(bal & 0xffffffffull);
      wp.y = (u32)(bal >> 32);
      *(uint2*)&Cbits[(((f * 64 + (dt >> 1)) * 512) + v) * 4 + (dt & 1) * 2] = wp;
    }
  }
  __syncthreads();
#pragma unroll
  for (int p = 0; p < 16; ++p) {
    int q = t + 256 * p;
    int jj = q >> 6, ii = q & 63;  // jj uniform per wave, ii == lane == v-offset
    float xv = (float)tile[ii * 65 + jj];
    u64 bal = __ballot(xv < 0.f);  // bit l <-> v = v0 + l
    if (lane == 0) {
      int d = d0 + jj;
      uint2 wp;
      wp.x = (u32)(bal & 0xffffffffull);
      wp.y = (u32)(bal >> 32);
      *(uint2*)&CbTb[((long)f * D + d) * 16 + vt * 2] = wp;
    }
  }
}

// ---------------------------------------------------------------------------
// init (bit-pack inputs + init estimates; raise has_zero if any est zero)
// ---------------------------------------------------------------------------
__global__ void k_init_pack(const float* __restrict__ inputs, const float* __restrict__ ie,
                            u32* __restrict__ in_bits, u32* __restrict__ es0,
                            u32* __restrict__ ez0, int* __restrict__ flags) {
  int tid = blockIdx.x * blockDim.x + threadIdx.x;
  int lane = tid & 63;
  int gw = tid >> 6;
  int NW = (gridDim.x * blockDim.x) >> 6;
  const int IN_W = B * (D / 64);       // 8192 chunks
  const int EST_W = B * F * (D / 64);  // 24576
  for (int c = gw; c < IN_W + EST_W; c += NW) {
    if (c < IN_W) {
      int b = c >> 7, dc = c & 127;
      float x = inputs[(long)b * D + dc * 64 + lane];
      u64 bal = __ballot(x < 0.f);
      if (lane == 0) {
        in_bits[b * DW + dc * 2] = (u32)(bal & 0xffffffffull);
        in_bits[b * DW + dc * 2 + 1] = (u32)(bal >> 32);
      }
    } else {
      int cc = c - IN_W;
      int bf = cc >> 7, dc = cc & 127;  // bf = b*F + f
      float x = ie[(long)bf * D + dc * 64 + lane];
      u64 bs = __ballot(x < 0.f);
      u64 bz = __ballot(x == 0.f);
      if (lane == 0) {
        es0[bf * DW + dc * 2] = (u32)(bs & 0xffffffffull);
        es0[bf * DW + dc * 2 + 1] = (u32)(bs >> 32);
        ez0[bf * DW + dc * 2] = (u32)(bz & 0xffffffffull);
        ez0[bf * DW + dc * 2 + 1] = (u32)(bz >> 32);
        if (bz) atomicOr(&flags[16], 1);
      }
    }
  }
}

// ---------------------------------------------------------------------------
// software grid barrier. Release fence (L2 writeback) before arrival; RELAXED
// poll (no per-poll invalidate — r3 lesson); ONE acquire fence (invalidate)
// after exit. flags[32]=counter, flags[40]=gen (separate line from flags[0..16]).
// Safe: 192 blocks <= 256 CUs, 45KB LDS -> all co-resident.
// ---------------------------------------------------------------------------
__device__ inline void grid_sync(int* counter, int* gen) {
  __syncthreads();
  if (threadIdx.x == 0) {
    __builtin_amdgcn_fence(__ATOMIC_RELEASE, "agent");  // wb dirty L2 -> IC
    int g = __hip_atomic_load(gen, __ATOMIC_RELAXED, __HIP_MEMORY_SCOPE_AGENT);
    int a = __hip_atomic_fetch_add(counter, 1, __ATOMIC_RELAXED, __HIP_MEMORY_SCOPE_AGENT);
    if (a == NBLK - 1) {
      __hip_atomic_store(counter, 0, __ATOMIC_RELAXED, __HIP_MEMORY_SCOPE_AGENT);
      __hip_atomic_store(gen, g + 1, __ATOMIC_RELAXED, __HIP_MEMORY_SCOPE_AGENT);
    } else {
      while (__hip_atomic_load(gen, __ATOMIC_RELAXED, __HIP_MEMORY_SCOPE_AGENT) == g)
        __builtin_amdgcn_s_sleep(4);
    }
    __builtin_amdgcn_fence(__ATOMIC_ACQUIRE, "agent");  // invalidate stale (ONCE)
  }
  __syncthreads();
}

// ---------------------------------------------------------------------------
// fused persistent kernel: 192 blocks x 512 threads (8 waves/block, 2/SIMD).
// per iter: sim phase (bit popcount, 1536 waves) -> barrier -> upd phase
// (exact 256h+l bf16 MFMA, r6 8-warp layout) -> barrier -> uniform conv
// check. Tail: final projection + argmax. Phase bodies == r6 verified kernels.
// ---------------------------------------------------------------------------
__global__ __launch_bounds__(512) void k_fused(
    const u32* __restrict__ Cbits, const u32* __restrict__ in_bits,
    u32* __restrict__ es0, u32* __restrict__ ez0,
    u32* __restrict__ es1, u32* __restrict__ ez1,
    const u32* __restrict__ CbTb, int* __restrict__ sim,
    int* __restrict__ flags, int* __restrict__ out) {
  __shared__ __attribute__((aligned(16))) bf16_t lAh[64 * 88];   // [b][v]
  __shared__ __attribute__((aligned(16))) bf16_t lAl[64 * 88];   // [b][v]
  __shared__ __attribute__((aligned(16))) bf16_t lB[128 * 88];   // [d][v]

  int* bar_cnt = flags + 32;
  int* bar_gen = flags + 40;

  const int bid = blockIdx.x;
  const int t = threadIdx.x, lane = t & 63, w = t >> 6;
  const int lm = lane & 15, quad = lane >> 4;
  // sim-phase wave task: 1536 waves = (f, b, vg)
  const int gwv = bid * 8 + w;
  const int vg = gwv & 7, bb = (gwv >> 3) & 63, fs = gwv >> 9;
  // upd-phase block task: 192 blocks = (f, dt); 8 warps = (wm b-half, wd d-col)
  const int fu = bid >> 6, dt = bid & 63, d0 = dt * 128;
  const int wd = w & 3, wm = w >> 2;

  int parity = 0;        // current est plane: 0 -> es0/ez0
  int done_iter = ITERS;
  int hz = aload(&flags[16]);

  auto sim_phase = [&](bool is_final) {
    const u32* es = parity ? es1 : es0;
    const u32* ez = parity ? ez1 : ez0;
    u32 As[4], Az[4];
    if (is_final) {
      const int i0 = (bb * F + fs) * DW;
#pragma unroll
      for (int r = 0; r < 4; ++r) As[r] = es[i0 + r * 64 + lane];
      if (hz) {
#pragma unroll
        for (int r = 0; r < 4; ++r) Az[r] = ~ez[i0 + r * 64 + lane];
      }
    } else {
      const int f1 = (fs + 1) % 3, f2 = (fs + 2) % 3;
      const int a0 = (bb * F + f1) * DW, a1 = (bb * F + f2) * DW;
      const int n0 = bb * DW;
#pragma unroll
      for (int r = 0; r < 4; ++r) {
        int o = r * 64 + lane;
        As[r] = in_bits[n0 + o] ^ es[a0 + o] ^ es[a1 + o];
      }
      if (hz) {
#pragma unroll
        for (int r = 0; r < 4; ++r) {
          int o = r * 64 + lane;
          Az[r] = ~(ez[a0 + o] | ez[a1 + o]);
        }
      }
    }

    int nzc = D;
    if (hz) {
      int p0 = 0;
#pragma unroll
      for (int r = 0; r < 4; ++r) p0 += __popc(Az[r]);
      for (int off = 32; off; off >>= 1) p0 += __shfl_xor(p0, off, 64);
      nzc = p0;
    }

    int acc = 0;
    const uint4* Cp = (const uint4*)Cbits + ((long)fs * 64) * 512 + vg * 64 + lane;
    if (!hz) {
#pragma unroll
      for (int r = 0; r < 4; ++r) {
#pragma unroll
        for (int i = 0; i < 16; ++i) {
          uint4 c = Cp[(r * 16 + i) * 512];
          const int k = i * 4;
          u32 a;
          a = (u32)__builtin_amdgcn_readlane((int)As[r], k + 0); acc += __popc(c.x ^ a);
          a = (u32)__builtin_amdgcn_readlane((int)As[r], k + 1); acc += __popc(c.y ^ a);
          a = (u32)__builtin_amdgcn_readlane((int)As[r], k + 2); acc += __popc(c.z ^ a);
          a = (u32)__builtin_amdgcn_readlane((int)As[r], k + 3); acc += __popc(c.w ^ a);
        }
      }
    } else {
#pragma unroll
      for (int r = 0; r < 4; ++r) {
#pragma unroll
        for (int i = 0; i < 16; ++i) {
          uint4 c = Cp[(r * 16 + i) * 512];
          const int k = i * 4;
          u32 a, z;
          a = (u32)__builtin_amdgcn_readlane((int)As[r], k + 0);
          z = (u32)__builtin_amdgcn_readlane((int)Az[r], k + 0); acc += __popc((c.x ^ a) & z);
          a = (u32)__builtin_amdgcn_readlane((int)As[r], k + 1);
          z = (u32)__builtin_amdgcn_readlane((int)Az[r], k + 1); acc += __popc((c.y ^ a) & z);
          a = (u32)__builtin_amdgcn_readlane((int)As[r], k + 2);
          z = (u32)__builtin_amdgcn_readlane((int)Az[r], k + 2); acc += __popc((c.z ^ a) & z);
          a = (u32)__builtin_amdgcn_readlane((int)As[r], k + 3);
          z = (u32)__builtin_amdgcn_readlane((int)Az[r], k + 3); acc += __popc((c.w ^ a) & z);
        }
      }
    }
    sim[(fs * B + bb) * V + vg * 64 + lane] = nzc - 2 * acc;
  };

  auto upd_phase = [&](int j) {
    const u32* esIn = parity ? es1 : es0;
    const u32* ezIn = parity ? ez1 : ez0;
    u32* esOut = parity ? es0 : es1;
    u32* ezOut = parity ? ez0 : ez1;
    const int* simf = sim + fu * (B * V);

    f32x4 zero = {0.f, 0.f, 0.f, 0.f};
    f32x4 accH[2][2], accL[2][2];
#pragma unroll
    for (int m = 0; m < 2; ++m)
#pragma unroll
      for (int nt = 0; nt < 2; ++nt) { accH[m][nt] = zero; accL[m][nt] = zero; }

    for (int c = 0; c < 8; ++c) {
      const int vb = c * 64;
      __syncthreads();
      // stage A: 64 b x 64 v ints -> h/l bf16 split (512 threads, 8 ints each)
      {
        int b8 = t >> 3, vv = (t & 7) * 8;
        const int* sp = simf + b8 * V + vb + vv;
        int4 sa = ((const int4*)sp)[0];
        int4 sb = ((const int4*)sp)[1];
        int si[8] = {sa.x, sa.y, sa.z, sa.w, sb.x, sb.y, sb.z, sb.w};
#pragma unroll
        for (int i = 0; i < 8; ++i) {
          lAh[b8 * 88 + vv + i] = (bf16_t)(float)(si[i] >> 8);
          lAl[b8 * 88 + vv + i] = (bf16_t)(float)(si[i] & 255);
        }
      }
      // stage B: expand +-1 bf16 from v-bit-packed codebook plane (L2-hot)
#pragma unroll
      for (int p = 0; p < 2; ++p) {
        int q = t + 512 * p;
        int r = q >> 3, vv = (q & 7) * 8;
        u32 bits = CbTb[((long)fu * D + d0 + r) * 16 + ((vb + vv) >> 5)];
        int sh = (vb + vv) & 31;
        u16x8 o;
#pragma unroll
        for (int i = 0; i < 8; ++i)
          o[i] = (u16)(0x3F80u | (((bits >> (sh + i)) & 1u) << 15));  // +-1.0 bf16
        *(u16x8*)&lB[r * 88 + vv] = o;
      }
      __syncthreads();
#pragma unroll
      for (int ks2 = 0; ks2 < 2; ++ks2) {
        const int kb = ks2 * 32 + quad * 8;
        bf16x8 bf0 = *(const bf16x8*)&lB[(wd * 32 + lm) * 88 + kb];
        bf16x8 bf1 = *(const bf16x8*)&lB[(wd * 32 + 16 + lm) * 88 + kb];
#pragma unroll
        for (int m = 0; m < 2; ++m) {
          const int mt = wm * 2 + m;
          bf16x8 ah = *(const bf16x8*)&lAh[(mt * 16 + lm) * 88 + kb];
          bf16x8 al = *(const bf16x8*)&lAl[(mt * 16 + lm) * 88 + kb];
          accH[m][0] = __builtin_amdgcn_mfma_f32_16x16x32_bf16(ah, bf0, accH[m][0], 0, 0, 0);
          accH[m][1] = __builtin_amdgcn_mfma_f32_16x16x32_bf16(ah, bf1, accH[m][1], 0, 0, 0);
          accL[m][0] = __builtin_amdgcn_mfma_f32_16x16x32_bf16(al, bf0, accL[m][0], 0, 0, 0);
          accL[m][1] = __builtin_amdgcn_mfma_f32_16x16x32_bf16(al, bf1, accL[m][1], 0, 0, 0);
        }
      }
    }
    // epilogue: ballot bit (quad*16+lm) of pass nt -> bit (nt*16+lm) of word W
    const int W = dt * 4 + wd;
    bool anyd = false, zf = false;
#pragma unroll
    for (int m = 0; m < 2; ++m)
#pragma unroll
      for (int r = 0; r < 4; ++r) {
        float v0 = 256.f * accH[m][0][r] + accL[m][0][r];
        float v1 = 256.f * accH[m][1][r] + accL[m][1][r];
        u64 s0 = __ballot(v0 < 0.f);
        u64 s1 = __ballot(v1 < 0.f);
        u64 z0 = __ballot(v0 == 0.f);
        u64 z1 = __ballot(v1 == 0.f);
        zf |= ((z0 | z1) != 0ull);
        if (lm == 0) {
          u32 ws = (u32)((s0 >> (quad * 16)) & 0xffffull) |
                   (((u32)((s1 >> (quad * 16)) & 0xffffull)) << 16);
          u32 wz = (u32)((z0 >> (quad * 16)) & 0xffffull) |
                   (((u32)((z1 >> (quad * 16)) & 0xffffull)) << 16);
          int b = (wm * 2 + m) * 16 + quad * 4 + r;
          int idx = (b * F + fu) * DW + W;
          anyd |= (esIn[idx] != ws) || (ezIn[idx] != wz);
          esOut[idx] = ws;
          ezOut[idx] = wz;
        }
      }
    if (__any(anyd) && lane == 0) atomicOr(&flags[j], 1);
    if (zf && lane == 0) atomicOr(&flags[16], 1);
  };

  for (int j = 0; j < ITERS; ++j) {
    sim_phase(false);
    grid_sync(bar_cnt, bar_gen);
    upd_phase(j);
    grid_sync(bar_cnt, bar_gen);
    int conv = aload(&flags[j]);  // atomic relaxed: vector path, bypass scalar cache
    hz = aload(&flags[16]);
    parity ^= 1;
    if (conv == 0) { done_iter = j; break; }  // uniform across grid
  }

  sim_phase(true);  // final projection with newest est (plane = parity)
  grid_sync(bar_cnt, bar_gen);

  // argmax phase: block bid -> (b,f), first wave only
  if (t < 64) {
    int b = bid / F, f = bid % F;
    const int* row = sim + (f * B + b) * V;
    int best = -2147483647;
    int bidx = 0;
#pragma unroll
    for (int i = 0; i < V / 64; ++i) {
      int v = lane + 64 * i;  // ascending within lane -> strict > keeps first max
      int x = row[v];
      if (x > best) { best = x; bidx = v; }
    }
    for (int off = 32; off; off >>= 1) {
      int ov = __shfl_down(best, off, 64);
      int oi = __shfl_down(bidx, off, 64);
      if (ov > best || (ov == best && oi < bidx)) { best = ov; bidx = oi; }
    }
    if (lane == 0) out[b * F + f] = bidx;
  }
  if (bid == 0 && t == 0) {
    int cnt = (done_iter < ITERS) ? (done_iter + 1) : ITERS;
    out[B * F] = cnt - 1;
  }
}

// ---------------------------------------------------------------------------
extern "C" void kernel_launch(void* const* d_in, const int* in_sizes, int n_in,
                              void* d_out, int out_size, void* d_ws, size_t ws_size,
                              hipStream_t stream) {
  const float* inputs    = (const float*)d_in[0];  // (B, D)
  const float* init_est  = (const float*)d_in[1];  // (B, F, D)
  const float* codebooks = (const float*)d_in[2];  // (F, V, D)

  char* w = (char*)d_ws;
  size_t o = 0;
  auto alloc = [&](size_t bytes) -> void* {
    void* p = w + o;
    o = (o + bytes + 255) & ~(size_t)255;
    return p;
  };
  u32* Cbits   = (u32*)alloc((size_t)F * 64 * 512 * 4 * 4);  // d-bit-packed
  u32* CbTb    = (u32*)alloc((size_t)F * D * 16 * 4);        // v-bit-packed
  u32* in_bits = (u32*)alloc((size_t)B * DW * 4);
  u32* es0     = (u32*)alloc((size_t)B * F * DW * 4);
  u32* ez0     = (u32*)alloc((size_t)B * F * DW * 4);
  u32* es1     = (u32*)alloc((size_t)B * F * DW * 4);
  u32* ez1     = (u32*)alloc((size_t)B * F * DW * 4);
  int* sim     = (int*)alloc((size_t)F * B * V * 4);
  int* flags   = (int*)alloc(256);

  k_init_tr<<<dim3(128, 8, 3), 256, 0, stream>>>(codebooks, Cbits, CbTb, flags);
  k_init_pack<<<1024, 256, 0, stream>>>(inputs, init_est, in_bits, es0, ez0, flags);
  k_fused<<<NBLK, 512, 0, stream>>>(Cbits, in_bits, es0, ez0, es1, ez1, CbTb, sim,
                                    flags, (int*)d_out);
}

// Round 8
// 657.975 us; speedup vs baseline: 1.0416x; 1.0416x over previous
//
#include <hip/hip_runtime.h>

#define F 3
#define V 512
#define D 8192
#define B 64
#define ITERS 10
#define DW 256   // u32 words per D-row (D/32)
#define NBLK 192
#define ESTW (B * F * DW)   // words per est plane (49152)
#define SIMW (F * B * V)    // ints per sim slice (98304)

typedef __bf16 bf16_t;
typedef __bf16 bf16x8 __attribute__((ext_vector_type(8)));
typedef float f32x4 __attribute__((ext_vector_type(4)));
typedef unsigned int u32;
typedef unsigned short u16;
typedef u16 u16x8 __attribute__((ext_vector_type(8)));
typedef unsigned long long u64;

// ---------------------------------------------------------------------------
// Values are in {0,+1,-1}. sign bit s=1 <=> v<0; zero bit z=1 <=> v==0.
// dot(A,c) = nzc - 2*popc((As ^ cs) & ~Az)  (exact integers).
//
// Rotating-buffer coherence (r7 post-mortem): the per-barrier ACQUIRE fence
// (L1/L2 invalidate, 21x192 of them) forced ~30MB of latency-bound refetch
// and was the residual cost of the persistent design. v3: sim and est planes
// are allocated PER ITERATION (write-once). A consumer's cache can never
// hold a stale line of a fresh buffer (never touched -> first access misses
// to the coherent point, where the producer's release fence put the data).
// So: writer release fence only; NO reader acquire fence; barrier gen and
// flags via relaxed agent atomics (bypass cache); everything else plain
// cached vectorized loads. Read-only bit planes stay L2-warm all kernel.
// ---------------------------------------------------------------------------

__device__ inline int aload(const int* p) {
  return __hip_atomic_load((int*)p, __ATOMIC_RELAXED, __HIP_MEMORY_SCOPE_AGENT);
}

// ---------------------------------------------------------------------------
// init: codebook bit-pack both ways + flag/barrier zeroing.
// Cbits[f][wc][v][j]: d-bit-packed (sim phase, uint4-tiled over d-words)
// CbTb[f][d][vw]:     v-bit-packed (upd phase B-operand LDS expansion)
// ---------------------------------------------------------------------------
__global__ __launch_bounds__(256) void k_init_tr(const float* __restrict__ Csrc,
                                                 u32* __restrict__ Cbits,
                                                 u32* __restrict__ CbTb,
                                                 int* __restrict__ flags) {
  int f = blockIdx.z, vt = blockIdx.y, dt = blockIdx.x;
  __shared__ bf16_t tile[64 * 65];
  int t = threadIdx.x;
  int lane = t & 63;
  int v0 = vt * 64, d0 = dt * 64;
  if (f == 0 && vt == 0 && dt == 0 && t < 64) flags[t] = 0;
#pragma unroll
  for (int p = 0; p < 16; ++p) {
    int q = t + 256 * p;
    int i = q >> 6, j = q & 63;  // j == lane, i uniform per wave
    float x = Csrc[((long)(f * V + v0 + i)) * D + d0 + j];
    tile[i * 65 + j] = (bf16_t)x;
    u64 bal = __ballot(x < 0.f);  // bit l <-> d = d0 + l
    if (lane == 0) {
      int v = v0 + i;
      uint2 wp;
      wp.x = (u32)(bal & 0xffffffffull);
      wp.y = (u32)(bal >> 32);
      *(uint2*)&Cbits[(((f * 64 + (dt >> 1)) * 512) + v) * 4 + (dt & 1) * 2] = wp;
    }
  }
  __syncthreads();
#pragma unroll
  for (int p = 0; p < 16; ++p) {
    int q = t + 256 * p;
    int jj = q >> 6, ii = q & 63;  // jj uniform per wave, ii == lane == v-offset
    float xv = (float)tile[ii * 65 + jj];
    u64 bal = __ballot(xv < 0.f);  // bit l <-> v = v0 + l
    if (lane == 0) {
      int d = d0 + jj;
      uint2 wp;
      wp.x = (u32)(bal & 0xffffffffull);
      wp.y = (u32)(bal >> 32);
      *(uint2*)&CbTb[((long)f * D + d) * 16 + vt * 2] = wp;
    }
  }
}

// ---------------------------------------------------------------------------
// init (bit-pack inputs + init estimates into plane 0; raise has_zero)
// ---------------------------------------------------------------------------
__global__ void k_init_pack(const float* __restrict__ inputs, const float* __restrict__ ie,
                            u32* __restrict__ in_bits, u32* __restrict__ es0,
                            u32* __restrict__ ez0, int* __restrict__ flags) {
  int tid = blockIdx.x * blockDim.x + threadIdx.x;
  int lane = tid & 63;
  int gw = tid >> 6;
  int NW = (gridDim.x * blockDim.x) >> 6;
  const int IN_W = B * (D / 64);       // 8192 chunks
  const int EST_W = B * F * (D / 64);  // 24576
  for (int c = gw; c < IN_W + EST_W; c += NW) {
    if (c < IN_W) {
      int b = c >> 7, dc = c & 127;
      float x = inputs[(long)b * D + dc * 64 + lane];
      u64 bal = __ballot(x < 0.f);
      if (lane == 0) {
        in_bits[b * DW + dc * 2] = (u32)(bal & 0xffffffffull);
        in_bits[b * DW + dc * 2 + 1] = (u32)(bal >> 32);
      }
    } else {
      int cc = c - IN_W;
      int bf = cc >> 7, dc = cc & 127;  // bf = b*F + f
      float x = ie[(long)bf * D + dc * 64 + lane];
      u64 bs = __ballot(x < 0.f);
      u64 bz = __ballot(x == 0.f);
      if (lane == 0) {
        es0[bf * DW + dc * 2] = (u32)(bs & 0xffffffffull);
        es0[bf * DW + dc * 2 + 1] = (u32)(bs >> 32);
        ez0[bf * DW + dc * 2] = (u32)(bz & 0xffffffffull);
        ez0[bf * DW + dc * 2 + 1] = (u32)(bz >> 32);
        if (bz) atomicOr(&flags[16], 1);
      }
    }
  }
}

// ---------------------------------------------------------------------------
// software grid barrier. Release fence (wbl2) before arrival; RELAXED poll;
// NO acquire fence (rotating write-once buffers make it unnecessary).
// flags[32]=counter, flags[40]=gen. 192 blocks co-resident -> no deadlock.
// ---------------------------------------------------------------------------
__device__ inline void grid_sync(int* counter, int* gen) {
  __syncthreads();
  if (threadIdx.x == 0) {
    __builtin_amdgcn_fence(__ATOMIC_RELEASE, "agent");  // wb dirty L2 -> coherent pt
    int g = __hip_atomic_load(gen, __ATOMIC_RELAXED, __HIP_MEMORY_SCOPE_AGENT);
    int a = __hip_atomic_fetch_add(counter, 1, __ATOMIC_RELAXED, __HIP_MEMORY_SCOPE_AGENT);
    if (a == NBLK - 1) {
      __hip_atomic_store(counter, 0, __ATOMIC_RELAXED, __HIP_MEMORY_SCOPE_AGENT);
      __hip_atomic_store(gen, g + 1, __ATOMIC_RELAXED, __HIP_MEMORY_SCOPE_AGENT);
    } else {
      while (__hip_atomic_load(gen, __ATOMIC_RELAXED, __HIP_MEMORY_SCOPE_AGENT) == g)
        __builtin_amdgcn_s_sleep(4);
    }
  }
  __syncthreads();
}

// ---------------------------------------------------------------------------
// fused persistent kernel: 192 blocks x 512 threads (8 waves/block, 2/SIMD).
// per iter j: sim phase (bit popcount) writes sim[j] -> barrier -> upd phase
// (exact 256h+l bf16 MFMA) reads sim[j]/est[j], writes est[j+1] -> barrier
// -> uniform conv check. Tail: final projection into sim[fin] + argmax.
// ---------------------------------------------------------------------------
__global__ __launch_bounds__(512) void k_fused(
    const u32* __restrict__ Cbits, const u32* __restrict__ in_bits,
    u32* __restrict__ esB, u32* __restrict__ ezB,
    const u32* __restrict__ CbTb, int* __restrict__ simB,
    int* __restrict__ flags, int* __restrict__ out) {
  __shared__ __attribute__((aligned(16))) bf16_t lAh[64 * 88];   // [b][v]
  __shared__ __attribute__((aligned(16))) bf16_t lAl[64 * 88];   // [b][v]
  __shared__ __attribute__((aligned(16))) bf16_t lB[128 * 88];   // [d][v]

  int* bar_cnt = flags + 32;
  int* bar_gen = flags + 40;

  const int bid = blockIdx.x;
  const int t = threadIdx.x, lane = t & 63, w = t >> 6;
  const int lm = lane & 15, quad = lane >> 4;
  // sim-phase wave task: 1536 waves = (f, b, vg)
  const int gwv = bid * 8 + w;
  const int vg = gwv & 7, bb = (gwv >> 3) & 63, fs = gwv >> 9;
  // upd-phase block task: 192 blocks = (f, dt); 8 warps = (wm b-half, wd d-col)
  const int fu = bid >> 6, dt = bid & 63, d0 = dt * 128;
  const int wd = w & 3, wm = w >> 2;

  int hz = aload(&flags[16]);

  auto sim_phase = [&](const u32* es, const u32* ez, int* simOut, bool is_final) {
    u32 As[4], Az[4];
    if (is_final) {
      const int i0 = (bb * F + fs) * DW;
#pragma unroll
      for (int r = 0; r < 4; ++r) As[r] = es[i0 + r * 64 + lane];
      if (hz) {
#pragma unroll
        for (int r = 0; r < 4; ++r) Az[r] = ~ez[i0 + r * 64 + lane];
      }
    } else {
      const int f1 = (fs + 1) % 3, f2 = (fs + 2) % 3;
      const int a0 = (bb * F + f1) * DW, a1 = (bb * F + f2) * DW;
      const int n0 = bb * DW;
#pragma unroll
      for (int r = 0; r < 4; ++r) {
        int o = r * 64 + lane;
        As[r] = in_bits[n0 + o] ^ es[a0 + o] ^ es[a1 + o];
      }
      if (hz) {
#pragma unroll
        for (int r = 0; r < 4; ++r) {
          int o = r * 64 + lane;
          Az[r] = ~(ez[a0 + o] | ez[a1 + o]);
        }
      }
    }

    int nzc = D;
    if (hz) {
      int p0 = 0;
#pragma unroll
      for (int r = 0; r < 4; ++r) p0 += __popc(Az[r]);
      for (int off = 32; off; off >>= 1) p0 += __shfl_xor(p0, off, 64);
      nzc = p0;
    }

    int acc = 0;
    const uint4* Cp = (const uint4*)Cbits + ((long)fs * 64) * 512 + vg * 64 + lane;
    if (!hz) {
#pragma unroll
      for (int r = 0; r < 4; ++r) {
#pragma unroll
        for (int i = 0; i < 16; ++i) {
          uint4 c = Cp[(r * 16 + i) * 512];
          const int k = i * 4;
          u32 a;
          a = (u32)__builtin_amdgcn_readlane((int)As[r], k + 0); acc += __popc(c.x ^ a);
          a = (u32)__builtin_amdgcn_readlane((int)As[r], k + 1); acc += __popc(c.y ^ a);
          a = (u32)__builtin_amdgcn_readlane((int)As[r], k + 2); acc += __popc(c.z ^ a);
          a = (u32)__builtin_amdgcn_readlane((int)As[r], k + 3); acc += __popc(c.w ^ a);
        }
      }
    } else {
#pragma unroll
      for (int r = 0; r < 4; ++r) {
#pragma unroll
        for (int i = 0; i < 16; ++i) {
          uint4 c = Cp[(r * 16 + i) * 512];
          const int k = i * 4;
          u32 a, z;
          a = (u32)__builtin_amdgcn_readlane((int)As[r], k + 0);
          z = (u32)__builtin_amdgcn_readlane((int)Az[r], k + 0); acc += __popc((c.x ^ a) & z);
          a = (u32)__builtin_amdgcn_readlane((int)As[r], k + 1);
          z = (u32)__builtin_amdgcn_readlane((int)Az[r], k + 1); acc += __popc((c.y ^ a) & z);
          a = (u32)__builtin_amdgcn_readlane((int)As[r], k + 2);
          z = (u32)__builtin_amdgcn_readlane((int)Az[r], k + 2); acc += __popc((c.z ^ a) & z);
          a = (u32)__builtin_amdgcn_readlane((int)As[r], k + 3);
          z = (u32)__builtin_amdgcn_readlane((int)Az[r], k + 3); acc += __popc((c.w ^ a) & z);
        }
      }
    }
    simOut[(fs * B + bb) * V + vg * 64 + lane] = nzc - 2 * acc;
  };

  auto upd_phase = [&](const int* simIn, const u32* esIn, const u32* ezIn,
                       u32* esOut, u32* ezOut, int j) {
    const int* simf = simIn + fu * (B * V);

    f32x4 zero = {0.f, 0.f, 0.f, 0.f};
    f32x4 accH[2][2], accL[2][2];
#pragma unroll
    for (int m = 0; m < 2; ++m)
#pragma unroll
      for (int nt = 0; nt < 2; ++nt) { accH[m][nt] = zero; accL[m][nt] = zero; }

    for (int c = 0; c < 8; ++c) {
      const int vb = c * 64;
      __syncthreads();
      // stage A: 64 b x 64 v ints -> h/l bf16 split (512 threads, 8 ints each)
      {
        int b8 = t >> 3, vv = (t & 7) * 8;
        const int* sp = simf + b8 * V + vb + vv;
        int4 sa = ((const int4*)sp)[0];
        int4 sb = ((const int4*)sp)[1];
        int si[8] = {sa.x, sa.y, sa.z, sa.w, sb.x, sb.y, sb.z, sb.w};
#pragma unroll
        for (int i = 0; i < 8; ++i) {
          lAh[b8 * 88 + vv + i] = (bf16_t)(float)(si[i] >> 8);
          lAl[b8 * 88 + vv + i] = (bf16_t)(float)(si[i] & 255);
        }
      }
      // stage B: expand +-1 bf16 from v-bit-packed codebook plane (L2-hot)
#pragma unroll
      for (int p = 0; p < 2; ++p) {
        int q = t + 512 * p;
        int r = q >> 3, vv = (q & 7) * 8;
        u32 bits = CbTb[((long)fu * D + d0 + r) * 16 + ((vb + vv) >> 5)];
        int sh = (vb + vv) & 31;
        u16x8 o;
#pragma unroll
        for (int i = 0; i < 8; ++i)
          o[i] = (u16)(0x3F80u | (((bits >> (sh + i)) & 1u) << 15));  // +-1.0 bf16
        *(u16x8*)&lB[r * 88 + vv] = o;
      }
      __syncthreads();
#pragma unroll
      for (int ks2 = 0; ks2 < 2; ++ks2) {
        const int kb = ks2 * 32 + quad * 8;
        bf16x8 bf0 = *(const bf16x8*)&lB[(wd * 32 + lm) * 88 + kb];
        bf16x8 bf1 = *(const bf16x8*)&lB[(wd * 32 + 16 + lm) * 88 + kb];
#pragma unroll
        for (int m = 0; m < 2; ++m) {
          const int mt = wm * 2 + m;
          bf16x8 ah = *(const bf16x8*)&lAh[(mt * 16 + lm) * 88 + kb];
          bf16x8 al = *(const bf16x8*)&lAl[(mt * 16 + lm) * 88 + kb];
          accH[m][0] = __builtin_amdgcn_mfma_f32_16x16x32_bf16(ah, bf0, accH[m][0], 0, 0, 0);
          accH[m][1] = __builtin_amdgcn_mfma_f32_16x16x32_bf16(ah, bf1, accH[m][1], 0, 0, 0);
          accL[m][0] = __builtin_amdgcn_mfma_f32_16x16x32_bf16(al, bf0, accL[m][0], 0, 0, 0);
          accL[m][1] = __builtin_amdgcn_mfma_f32_16x16x32_bf16(al, bf1, accL[m][1], 0, 0, 0);
        }
      }
    }
    // epilogue: ballot bit (quad*16+lm) of pass nt -> bit (nt*16+lm) of word W
    const int W = dt * 4 + wd;
    bool anyd = false, zf = false;
#pragma unroll
    for (int m = 0; m < 2; ++m)
#pragma unroll
      for (int r = 0; r < 4; ++r) {
        float v0 = 256.f * accH[m][0][r] + accL[m][0][r];
        float v1 = 256.f * accH[m][1][r] + accL[m][1][r];
        u64 s0 = __ballot(v0 < 0.f);
        u64 s1 = __ballot(v1 < 0.f);
        u64 z0 = __ballot(v0 == 0.f);
        u64 z1 = __ballot(v1 == 0.f);
        zf |= ((z0 | z1) != 0ull);
        if (lm == 0) {
          u32 ws = (u32)((s0 >> (quad * 16)) & 0xffffull) |
                   (((u32)((s1 >> (quad * 16)) & 0xffffull)) << 16);
          u32 wz = (u32)((z0 >> (quad * 16)) & 0xffffull) |
                   (((u32)((z1 >> (quad * 16)) & 0xffffull)) << 16);
          int b = (wm * 2 + m) * 16 + quad * 4 + r;
          int idx = (b * F + fu) * DW + W;
          anyd |= (esIn[idx] != ws) || (ezIn[idx] != wz);
          esOut[idx] = ws;
          ezOut[idx] = wz;
        }
      }
    if (__any(anyd) && lane == 0) atomicOr(&flags[j], 1);
    if (zf && lane == 0) atomicOr(&flags[16], 1);
  };

  int fin = ITERS;   // plane index of the final est (= iteration count)
  bool done = false;
  for (int j = 0; j < ITERS && !done; ++j) {
    sim_phase(esB + (size_t)j * ESTW, ezB + (size_t)j * ESTW,
              simB + (size_t)j * SIMW, false);
    grid_sync(bar_cnt, bar_gen);
    upd_phase(simB + (size_t)j * SIMW,
              esB + (size_t)j * ESTW, ezB + (size_t)j * ESTW,
              esB + (size_t)(j + 1) * ESTW, ezB + (size_t)(j + 1) * ESTW, j);
    grid_sync(bar_cnt, bar_gen);
    int conv = aload(&flags[j]);
    hz = aload(&flags[16]);
    if (conv == 0) { fin = j + 1; done = true; }  // uniform across grid
  }

  // final projection with newest est plane (index fin)
  sim_phase(esB + (size_t)fin * ESTW, ezB + (size_t)fin * ESTW,
            simB + (size_t)fin * SIMW, true);
  grid_sync(bar_cnt, bar_gen);

  // argmax phase: block bid -> (b,f), first wave only
  const int* simFin = simB + (size_t)fin * SIMW;
  if (t < 64) {
    int b = bid / F, f = bid % F;
    const int* row = simFin + (f * B + b) * V;
    int best = -2147483647;
    int bidx = 0;
#pragma unroll
    for (int i = 0; i < V / 64; ++i) {
      int v = lane + 64 * i;  // ascending within lane -> strict > keeps first max
      int x = row[v];
      if (x > best) { best = x; bidx = v; }
    }
    for (int off = 32; off; off >>= 1) {
      int ov = __shfl_down(best, off, 64);
      int oi = __shfl_down(bidx, off, 64);
      if (ov > best || (ov == best && oi < bidx)) { best = ov; bidx = oi; }
    }
    if (lane == 0) out[b * F + f] = bidx;
  }
  if (bid == 0 && t == 0) out[B * F] = fin - 1;
}

// ---------------------------------------------------------------------------
extern "C" void kernel_launch(void* const* d_in, const int* in_sizes, int n_in,
                              void* d_out, int out_size, void* d_ws, size_t ws_size,
                              hipStream_t stream) {
  const float* inputs    = (const float*)d_in[0];  // (B, D)
  const float* init_est  = (const float*)d_in[1];  // (B, F, D)
  const float* codebooks = (const float*)d_in[2];  // (F, V, D)

  char* w = (char*)d_ws;
  size_t o = 0;
  auto alloc = [&](size_t bytes) -> void* {
    void* p = w + o;
    o = (o + bytes + 255) & ~(size_t)255;
    return p;
  };
  u32* Cbits   = (u32*)alloc((size_t)F * 64 * 512 * 4 * 4);        // d-bit-packed
  u32* CbTb    = (u32*)alloc((size_t)F * D * 16 * 4);              // v-bit-packed
  u32* in_bits = (u32*)alloc((size_t)B * DW * 4);
  u32* esB     = (u32*)alloc((size_t)(ITERS + 1) * ESTW * 4);      // rotating planes
  u32* ezB     = (u32*)alloc((size_t)(ITERS + 1) * ESTW * 4);
  int* simB    = (int*)alloc((size_t)(ITERS + 1) * SIMW * 4);      // rotating slices
  int* flags   = (int*)alloc(256);

  k_init_tr<<<dim3(128, 8, 3), 256, 0, stream>>>(codebooks, Cbits, CbTb, flags);
  k_init_pack<<<1024, 256, 0, stream>>>(inputs, init_est, in_bits, esB, ezB, flags);
  k_fused<<<NBLK, 512, 0, stream>>>(Cbits, in_bits, esB, ezB, CbTb, simB,
                                    flags, (int*)d_out);
}

// Round 9
// 530.338 us; speedup vs baseline: 1.2923x; 1.2407x over previous
//
#include <hip/hip_runtime.h>

#define F 3
#define V 512
#define D 8192
#define B 64
#define ITERS 10
#define DW 256   // u32 words per D-row (D/32)
#define NBLK 192
#define ESTW (B * F * DW)   // words per est plane (49152)
#define SIMW (F * B * V)    // ints per sim slice (98304)

typedef __bf16 bf16_t;
typedef __bf16 bf16x8 __attribute__((ext_vector_type(8)));
typedef float f32x4 __attribute__((ext_vector_type(4)));
typedef unsigned int u32;
typedef unsigned short u16;
typedef u16 u16x8 __attribute__((ext_vector_type(8)));
typedef unsigned long long u64;

// ---------------------------------------------------------------------------
// Values are in {0,+1,-1}. sign bit s=1 <=> v<0; zero bit z=1 <=> v==0.
// dot(A,c) = nzc - 2*popc((As ^ cs) & ~Az)  (exact integers).
//
// Coherence design v4 (r8 post-mortem): FETCH is already cold-minimal; the
// residual stall is the barrier: 192 same-line IC RMWs (serialized) plus
// 192 buffer_wbl2 L2-writeback scans (release fence per block) per barrier,
// x21 barriers. v4 removes both:
//  - cross-phase WRITES are relaxed agent atomic stores (sc0 sc1 write-
//    through, committed at the coherent point). With rotating write-once
//    buffers, readers' plain cached loads miss (fresh lines) and fill from
//    the IC which already holds the data -> NO fence of any kind needed.
//    __syncthreads() at barrier entry emits s_waitcnt vmcnt(0) (compiler-
//    guaranteed before s_barrier), draining write-throughs before arrival.
//  - two-level tree barrier: 8 leaf counters (bid&7, own 64B lines) + root
//    + gen, monotonic relaxed atomics -> serialized RMW chain 192 -> 24+8.
// ---------------------------------------------------------------------------

__device__ inline int aload(const int* p) {
  return __hip_atomic_load((int*)p, __ATOMIC_RELAXED, __HIP_MEMORY_SCOPE_AGENT);
}
__device__ inline void astore(int* p, int v) {
  __hip_atomic_store(p, v, __ATOMIC_RELAXED, __HIP_MEMORY_SCOPE_AGENT);
}
__device__ inline void astoreu(u32* p, u32 v) {
  __hip_atomic_store(p, v, __ATOMIC_RELAXED, __HIP_MEMORY_SCOPE_AGENT);
}

// ---------------------------------------------------------------------------
// init: codebook bit-pack both ways + flag/barrier zeroing.
// Cbits[f][wc][v][j]: d-bit-packed (sim phase, uint4-tiled over d-words)
// CbTb[f][d][vw]:     v-bit-packed (upd phase B-operand LDS expansion)
// ---------------------------------------------------------------------------
__global__ __launch_bounds__(256) void k_init_tr(const float* __restrict__ Csrc,
                                                 u32* __restrict__ Cbits,
                                                 u32* __restrict__ CbTb,
                                                 int* __restrict__ flags) {
  int f = blockIdx.z, vt = blockIdx.y, dt = blockIdx.x;
  __shared__ bf16_t tile[64 * 65];
  int t = threadIdx.x;
  int lane = t & 63;
  int v0 = vt * 64, d0 = dt * 64;
  if (f == 0 && vt == 0 && dt == 0) flags[t] = 0;  // zero all 256 control ints
#pragma unroll
  for (int p = 0; p < 16; ++p) {
    int q = t + 256 * p;
    int i = q >> 6, j = q & 63;  // j == lane, i uniform per wave
    float x = Csrc[((long)(f * V + v0 + i)) * D + d0 + j];
    tile[i * 65 + j] = (bf16_t)x;
    u64 bal = __ballot(x < 0.f);  // bit l <-> d = d0 + l
    if (lane == 0) {
      int v = v0 + i;
      uint2 wp;
      wp.x = (u32)(bal & 0xffffffffull);
      wp.y = (u32)(bal >> 32);
      *(uint2*)&Cbits[(((f * 64 + (dt >> 1)) * 512) + v) * 4 + (dt & 1) * 2] = wp;
    }
  }
  __syncthreads();
#pragma unroll
  for (int p = 0; p < 16; ++p) {
    int q = t + 256 * p;
    int jj = q >> 6, ii = q & 63;  // jj uniform per wave, ii == lane == v-offset
    float xv = (float)tile[ii * 65 + jj];
    u64 bal = __ballot(xv < 0.f);  // bit l <-> v = v0 + l
    if (lane == 0) {
      int d = d0 + jj;
      uint2 wp;
      wp.x = (u32)(bal & 0xffffffffull);
      wp.y = (u32)(bal >> 32);
      *(uint2*)&CbTb[((long)f * D + d) * 16 + vt * 2] = wp;
    }
  }
}

// ---------------------------------------------------------------------------
// init (bit-pack inputs + init estimates into plane 0; raise has_zero)
// ---------------------------------------------------------------------------
__global__ void k_init_pack(const float* __restrict__ inputs, const float* __restrict__ ie,
                            u32* __restrict__ in_bits, u32* __restrict__ es0,
                            u32* __restrict__ ez0, int* __restrict__ flags) {
  int tid = blockIdx.x * blockDim.x + threadIdx.x;
  int lane = tid & 63;
  int gw = tid >> 6;
  int NW = (gridDim.x * blockDim.x) >> 6;
  const int IN_W = B * (D / 64);       // 8192 chunks
  const int EST_W = B * F * (D / 64);  // 24576
  for (int c = gw; c < IN_W + EST_W; c += NW) {
    if (c < IN_W) {
      int b = c >> 7, dc = c & 127;
      float x = inputs[(long)b * D + dc * 64 + lane];
      u64 bal = __ballot(x < 0.f);
      if (lane == 0) {
        in_bits[b * DW + dc * 2] = (u32)(bal & 0xffffffffull);
        in_bits[b * DW + dc * 2 + 1] = (u32)(bal >> 32);
      }
    } else {
      int cc = c - IN_W;
      int bf = cc >> 7, dc = cc & 127;  // bf = b*F + f
      float x = ie[(long)bf * D + dc * 64 + lane];
      u64 bs = __ballot(x < 0.f);
      u64 bz = __ballot(x == 0.f);
      if (lane == 0) {
        es0[bf * DW + dc * 2] = (u32)(bs & 0xffffffffull);
        es0[bf * DW + dc * 2 + 1] = (u32)(bs >> 32);
        ez0[bf * DW + dc * 2] = (u32)(bz & 0xffffffffull);
        ez0[bf * DW + dc * 2 + 1] = (u32)(bz >> 32);
        if (bz) atomicOr(&flags[16], 1);
      }
    }
  }
}

// ---------------------------------------------------------------------------
// two-level tree grid barrier, monotonic counters, all RELAXED atomics.
// flags[40]=gen, flags[48]=root, flags[64+16g]=leaf g (own 64B line each).
// No fences: cross-phase data is sc1 write-through (drained by the
// s_waitcnt vmcnt(0) the compiler emits for __syncthreads before arrival).
// 192 blocks co-resident (44KB LDS, 128 VGPR) -> no deadlock.
// ---------------------------------------------------------------------------
__device__ inline void grid_sync(int* flags, int* ep) {
  __syncthreads();  // emits s_waitcnt vmcnt(0) -> write-throughs at IC
  if (threadIdx.x == 0) {
    int e = *ep;
    int g = blockIdx.x & 7;
    int a = __hip_atomic_fetch_add(&flags[64 + g * 16], 1, __ATOMIC_RELAXED,
                                   __HIP_MEMORY_SCOPE_AGENT);
    if ((a % 24) == 23) {  // last of this leaf group
      int r = __hip_atomic_fetch_add(&flags[48], 1, __ATOMIC_RELAXED,
                                     __HIP_MEMORY_SCOPE_AGENT);
      if ((r % 8) == 7)    // last leaf overall -> flip generation
        __hip_atomic_store(&flags[40], e + 1, __ATOMIC_RELAXED,
                           __HIP_MEMORY_SCOPE_AGENT);
    }
    while (__hip_atomic_load(&flags[40], __ATOMIC_RELAXED,
                             __HIP_MEMORY_SCOPE_AGENT) < e + 1)
      __builtin_amdgcn_s_sleep(2);
    *ep = e + 1;
  }
  __syncthreads();
}

// ---------------------------------------------------------------------------
// fused persistent kernel: 192 blocks x 512 threads (8 waves/block, 2/SIMD).
// per iter j: sim phase (bit popcount) writes sim[j] (sc1) -> barrier ->
// upd phase (exact 256h+l bf16 MFMA) reads sim[j]/est[j] (plain, rotation-
// fresh), writes est[j+1] (sc1) -> barrier -> uniform conv check.
// Tail: final projection into sim[fin] + argmax.
// ---------------------------------------------------------------------------
__global__ __launch_bounds__(512) void k_fused(
    const u32* __restrict__ Cbits, const u32* __restrict__ in_bits,
    u32* __restrict__ esB, u32* __restrict__ ezB,
    const u32* __restrict__ CbTb, int* __restrict__ simB,
    int* __restrict__ flags, int* __restrict__ out) {
  __shared__ __attribute__((aligned(16))) bf16_t lAh[64 * 88];   // [b][v]
  __shared__ __attribute__((aligned(16))) bf16_t lAl[64 * 88];   // [b][v]
  __shared__ __attribute__((aligned(16))) bf16_t lB[128 * 88];   // [d][v]

  const int bid = blockIdx.x;
  const int t = threadIdx.x, lane = t & 63, w = t >> 6;
  const int lm = lane & 15, quad = lane >> 4;
  // sim-phase wave task: 1536 waves = (f, b, vg)
  const int gwv = bid * 8 + w;
  const int vg = gwv & 7, bb = (gwv >> 3) & 63, fs = gwv >> 9;
  // upd-phase block task: 192 blocks = (f, dt); 8 warps = (wm b-half, wd d-col)
  const int fu = bid >> 6, dt = bid & 63, d0 = dt * 128;
  const int wd = w & 3, wm = w >> 2;

  int ep = 0;  // barrier epoch
  int hz = aload(&flags[16]);

  auto sim_phase = [&](const u32* es, const u32* ez, int* simOut, bool is_final) {
    u32 As[4], Az[4];
    if (is_final) {
      const int i0 = (bb * F + fs) * DW;
#pragma unroll
      for (int r = 0; r < 4; ++r) As[r] = es[i0 + r * 64 + lane];
      if (hz) {
#pragma unroll
        for (int r = 0; r < 4; ++r) Az[r] = ~ez[i0 + r * 64 + lane];
      }
    } else {
      const int f1 = (fs + 1) % 3, f2 = (fs + 2) % 3;
      const int a0 = (bb * F + f1) * DW, a1 = (bb * F + f2) * DW;
      const int n0 = bb * DW;
#pragma unroll
      for (int r = 0; r < 4; ++r) {
        int o = r * 64 + lane;
        As[r] = in_bits[n0 + o] ^ es[a0 + o] ^ es[a1 + o];
      }
      if (hz) {
#pragma unroll
        for (int r = 0; r < 4; ++r) {
          int o = r * 64 + lane;
          Az[r] = ~(ez[a0 + o] | ez[a1 + o]);
        }
      }
    }

    int nzc = D;
    if (hz) {
      int p0 = 0;
#pragma unroll
      for (int r = 0; r < 4; ++r) p0 += __popc(Az[r]);
      for (int off = 32; off; off >>= 1) p0 += __shfl_xor(p0, off, 64);
      nzc = p0;
    }

    int acc = 0;
    const uint4* Cp = (const uint4*)Cbits + ((long)fs * 64) * 512 + vg * 64 + lane;
    if (!hz) {
#pragma unroll
      for (int r = 0; r < 4; ++r) {
#pragma unroll
        for (int i = 0; i < 16; ++i) {
          uint4 c = Cp[(r * 16 + i) * 512];
          const int k = i * 4;
          u32 a;
          a = (u32)__builtin_amdgcn_readlane((int)As[r], k + 0); acc += __popc(c.x ^ a);
          a = (u32)__builtin_amdgcn_readlane((int)As[r], k + 1); acc += __popc(c.y ^ a);
          a = (u32)__builtin_amdgcn_readlane((int)As[r], k + 2); acc += __popc(c.z ^ a);
          a = (u32)__builtin_amdgcn_readlane((int)As[r], k + 3); acc += __popc(c.w ^ a);
        }
      }
    } else {
#pragma unroll
      for (int r = 0; r < 4; ++r) {
#pragma unroll
        for (int i = 0; i < 16; ++i) {
          uint4 c = Cp[(r * 16 + i) * 512];
          const int k = i * 4;
          u32 a, z;
          a = (u32)__builtin_amdgcn_readlane((int)As[r], k + 0);
          z = (u32)__builtin_amdgcn_readlane((int)Az[r], k + 0); acc += __popc((c.x ^ a) & z);
          a = (u32)__builtin_amdgcn_readlane((int)As[r], k + 1);
          z = (u32)__builtin_amdgcn_readlane((int)Az[r], k + 1); acc += __popc((c.y ^ a) & z);
          a = (u32)__builtin_amdgcn_readlane((int)As[r], k + 2);
          z = (u32)__builtin_amdgcn_readlane((int)Az[r], k + 2); acc += __popc((c.z ^ a) & z);
          a = (u32)__builtin_amdgcn_readlane((int)As[r], k + 3);
          z = (u32)__builtin_amdgcn_readlane((int)Az[r], k + 3); acc += __popc((c.w ^ a) & z);
        }
      }
    }
    astore(&simOut[(fs * B + bb) * V + vg * 64 + lane], nzc - 2 * acc);
  };

  auto upd_phase = [&](const int* simIn, const u32* esIn, const u32* ezIn,
                       u32* esOut, u32* ezOut, int j) {
    const int* simf = simIn + fu * (B * V);

    f32x4 zero = {0.f, 0.f, 0.f, 0.f};
    f32x4 accH[2][2], accL[2][2];
#pragma unroll
    for (int m = 0; m < 2; ++m)
#pragma unroll
      for (int nt = 0; nt < 2; ++nt) { accH[m][nt] = zero; accL[m][nt] = zero; }

    for (int c = 0; c < 8; ++c) {
      const int vb = c * 64;
      __syncthreads();
      // stage A: 64 b x 64 v ints -> h/l bf16 split (512 threads, 8 ints each)
      {
        int b8 = t >> 3, vv = (t & 7) * 8;
        const int* sp = simf + b8 * V + vb + vv;
        int4 sa = ((const int4*)sp)[0];
        int4 sb = ((const int4*)sp)[1];
        int si[8] = {sa.x, sa.y, sa.z, sa.w, sb.x, sb.y, sb.z, sb.w};
#pragma unroll
        for (int i = 0; i < 8; ++i) {
          lAh[b8 * 88 + vv + i] = (bf16_t)(float)(si[i] >> 8);
          lAl[b8 * 88 + vv + i] = (bf16_t)(float)(si[i] & 255);
        }
      }
      // stage B: expand +-1 bf16 from v-bit-packed codebook plane (L2-hot)
#pragma unroll
      for (int p = 0; p < 2; ++p) {
        int q = t + 512 * p;
        int r = q >> 3, vv = (q & 7) * 8;
        u32 bits = CbTb[((long)fu * D + d0 + r) * 16 + ((vb + vv) >> 5)];
        int sh = (vb + vv) & 31;
        u16x8 o;
#pragma unroll
        for (int i = 0; i < 8; ++i)
          o[i] = (u16)(0x3F80u | (((bits >> (sh + i)) & 1u) << 15));  // +-1.0 bf16
        *(u16x8*)&lB[r * 88 + vv] = o;
      }
      __syncthreads();
#pragma unroll
      for (int ks2 = 0; ks2 < 2; ++ks2) {
        const int kb = ks2 * 32 + quad * 8;
        bf16x8 bf0 = *(const bf16x8*)&lB[(wd * 32 + lm) * 88 + kb];
        bf16x8 bf1 = *(const bf16x8*)&lB[(wd * 32 + 16 + lm) * 88 + kb];
#pragma unroll
        for (int m = 0; m < 2; ++m) {
          const int mt = wm * 2 + m;
          bf16x8 ah = *(const bf16x8*)&lAh[(mt * 16 + lm) * 88 + kb];
          bf16x8 al = *(const bf16x8*)&lAl[(mt * 16 + lm) * 88 + kb];
          accH[m][0] = __builtin_amdgcn_mfma_f32_16x16x32_bf16(ah, bf0, accH[m][0], 0, 0, 0);
          accH[m][1] = __builtin_amdgcn_mfma_f32_16x16x32_bf16(ah, bf1, accH[m][1], 0, 0, 0);
          accL[m][0] = __builtin_amdgcn_mfma_f32_16x16x32_bf16(al, bf0, accL[m][0], 0, 0, 0);
          accL[m][1] = __builtin_amdgcn_mfma_f32_16x16x32_bf16(al, bf1, accL[m][1], 0, 0, 0);
        }
      }
    }
    // epilogue: ballot bit (quad*16+lm) of pass nt -> bit (nt*16+lm) of word W
    const int W = dt * 4 + wd;
    bool anyd = false, zf = false;
#pragma unroll
    for (int m = 0; m < 2; ++m)
#pragma unroll
      for (int r = 0; r < 4; ++r) {
        float v0 = 256.f * accH[m][0][r] + accL[m][0][r];
        float v1 = 256.f * accH[m][1][r] + accL[m][1][r];
        u64 s0 = __ballot(v0 < 0.f);
        u64 s1 = __ballot(v1 < 0.f);
        u64 z0 = __ballot(v0 == 0.f);
        u64 z1 = __ballot(v1 == 0.f);
        zf |= ((z0 | z1) != 0ull);
        if (lm == 0) {
          u32 ws = (u32)((s0 >> (quad * 16)) & 0xffffull) |
                   (((u32)((s1 >> (quad * 16)) & 0xffffull)) << 16);
          u32 wz = (u32)((z0 >> (quad * 16)) & 0xffffull) |
                   (((u32)((z1 >> (quad * 16)) & 0xffffull)) << 16);
          int b = (wm * 2 + m) * 16 + quad * 4 + r;
          int idx = (b * F + fu) * DW + W;
          anyd |= (esIn[idx] != ws) || (ezIn[idx] != wz);
          astoreu(&esOut[idx], ws);
          astoreu(&ezOut[idx], wz);
        }
      }
    if (__any(anyd) && lane == 0) atomicOr(&flags[j], 1);
    if (zf && lane == 0) atomicOr(&flags[16], 1);
  };

  int fin = ITERS;   // plane index of the final est (= iteration count)
  bool done = false;
  for (int j = 0; j < ITERS && !done; ++j) {
    sim_phase(esB + (size_t)j * ESTW, ezB + (size_t)j * ESTW,
              simB + (size_t)j * SIMW, false);
    grid_sync(flags, &ep);
    upd_phase(simB + (size_t)j * SIMW,
              esB + (size_t)j * ESTW, ezB + (size_t)j * ESTW,
              esB + (size_t)(j + 1) * ESTW, ezB + (size_t)(j + 1) * ESTW, j);
    grid_sync(flags, &ep);
    int conv = aload(&flags[j]);
    hz = aload(&flags[16]);
    if (conv == 0) { fin = j + 1; done = true; }  // uniform across grid
  }

  // final projection with newest est plane (index fin)
  sim_phase(esB + (size_t)fin * ESTW, ezB + (size_t)fin * ESTW,
            simB + (size_t)fin * SIMW, true);
  grid_sync(flags, &ep);

  // argmax phase: block bid -> (b,f), first wave only. sim[fin] lines are
  // rotation-fresh for this block (it only wrote them via sc1) -> plain
  // loads miss to IC and read fresh data.
  const int* simFin = simB + (size_t)fin * SIMW;
  if (t < 64) {
    int b = bid / F, f = bid % F;
    const int* row = simFin + (f * B + b) * V;
    int best = -2147483647;
    int bidx = 0;
#pragma unroll
    for (int i = 0; i < V / 64; ++i) {
      int v = lane + 64 * i;  // ascending within lane -> strict > keeps first max
      int x = row[v];
      if (x > best) { best = x; bidx = v; }
    }
    for (int off = 32; off; off >>= 1) {
      int ov = __shfl_down(best, off, 64);
      int oi = __shfl_down(bidx, off, 64);
      if (ov > best || (ov == best && oi < bidx)) { best = ov; bidx = oi; }
    }
    if (lane == 0) out[b * F + f] = bidx;
  }
  if (bid == 0 && t == 0) out[B * F] = fin - 1;
}

// ---------------------------------------------------------------------------
extern "C" void kernel_launch(void* const* d_in, const int* in_sizes, int n_in,
                              void* d_out, int out_size, void* d_ws, size_t ws_size,
                              hipStream_t stream) {
  const float* inputs    = (const float*)d_in[0];  // (B, D)
  const float* init_est  = (const float*)d_in[1];  // (B, F, D)
  const float* codebooks = (const float*)d_in[2];  // (F, V, D)

  char* w = (char*)d_ws;
  size_t o = 0;
  auto alloc = [&](size_t bytes) -> void* {
    void* p = w + o;
    o = (o + bytes + 255) & ~(size_t)255;
    return p;
  };
  u32* Cbits   = (u32*)alloc((size_t)F * 64 * 512 * 4 * 4);        // d-bit-packed
  u32* CbTb    = (u32*)alloc((size_t)F * D * 16 * 4);              // v-bit-packed
  u32* in_bits = (u32*)alloc((size_t)B * DW * 4);
  u32* esB     = (u32*)alloc((size_t)(ITERS + 1) * ESTW * 4);      // rotating planes
  u32* ezB     = (u32*)alloc((size_t)(ITERS + 1) * ESTW * 4);
  int* simB    = (int*)alloc((size_t)(ITERS + 1) * SIMW * 4);      // rotating slices
  int* flags   = (int*)alloc(1024);                                // 256 control ints

  k_init_tr<<<dim3(128, 8, 3), 256, 0, stream>>>(codebooks, Cbits, CbTb, flags);
  k_init_pack<<<1024, 256, 0, stream>>>(inputs, init_est, in_bits, esB, ezB, flags);
  k_fused<<<NBLK, 512, 0, stream>>>(Cbits, in_bits, esB, ezB, CbTb, simB,
                                    flags, (int*)d_out);
}